// Round 2
// baseline (231.447 us; speedup 1.0000x reference)
//
#include <hip/hip_runtime.h>
#include <hip/hip_bf16.h>
#include <cstdint>

typedef __bf16 bf16x8 __attribute__((ext_vector_type(8)));
typedef float f32x4 __attribute__((ext_vector_type(4)));

#define E_DIM 256
#define H_DIM 512
#define TSTR 260   // padded f32 row stride for tsl/dsl (260*4B: +16B per row)

// ---------------- kernel 1: W1c -> bf16, chunk-major [c][h][kk] ----------------
// W1cc[c*16384 + h*32 + kk] = bf16(W1[(512 + c*32 + kk)*512 + h])
__global__ void w1c_kernel(const float* __restrict__ W1, __bf16* __restrict__ W1cc) {
    int t  = blockIdx.x * 256 + threadIdx.x;
    int h  = t & 511;
    int kk = (t >> 9) & 31;
    int c  = t >> 14;
    float v = W1[(size_t)(512 + c * 32 + kk) * H_DIM + h];
    W1cc[(size_t)c * 16384 + (size_t)h * 32 + kk] = (__bf16)v;
}

// ---------------- kernel 2: P = norm(t)@W1a + b1 ; Q = norm(d)@W1b (f32) -------
// l2-norm fused: dot on raw rows, scale at the end (normalization is linear).
__global__ void pq_kernel(const float* __restrict__ track, const float* __restrict__ det,
                          const float* __restrict__ W1, const float* __restrict__ b1,
                          float* __restrict__ P, float* __restrict__ Q) {
    __shared__ float xs[8 * E_DIM];
    __shared__ float scl[8];
    int blk = blockIdx.x;
    bool isP = blk < 128;
    int r0 = (isP ? blk : blk - 128) * 8;
    const float* src = isP ? track : det;
    int t = threadIdx.x;
    ((float4*)xs)[t] = ((const float4*)(src + (size_t)r0 * E_DIM))[t];
    __syncthreads();
    {   // per-row inverse norms: wave w reduces row w
        int w = t >> 6, lane = t & 63;
        float4 xv = ((const float4*)xs)[w * 64 + lane];
        float ss = xv.x*xv.x + xv.y*xv.y + xv.z*xv.z + xv.w*xv.w;
#pragma unroll
        for (int off = 32; off > 0; off >>= 1) ss += __shfl_xor(ss, off);
        if (lane == 0) scl[w] = 1.0f / fmaxf(sqrtf(ss), 1e-12f);
    }
    __syncthreads();

    int h = t;  // 0..511
    float acc[8];
#pragma unroll
    for (int r = 0; r < 8; ++r) acc[r] = 0.0f;
    float bias = isP ? b1[h] : 0.0f;
    const float* w = W1 + (isP ? 0 : (size_t)E_DIM * H_DIM) + h;
    const float4* xs4 = (const float4*)xs;  // [8][64]
    for (int e4 = 0; e4 < 64; ++e4) {
        int e = e4 * 4;
        float w0 = w[(size_t)(e + 0) * H_DIM];
        float w1v = w[(size_t)(e + 1) * H_DIM];
        float w2v = w[(size_t)(e + 2) * H_DIM];
        float w3v = w[(size_t)(e + 3) * H_DIM];
#pragma unroll
        for (int r = 0; r < 8; ++r) {
            float4 xv = xs4[r * 64 + e4];
            acc[r] += xv.x * w0 + xv.y * w1v + xv.z * w2v + xv.w * w3v;
        }
    }
    float* dst = (isP ? P : Q) + (size_t)r0 * H_DIM + h;
#pragma unroll
    for (int r = 0; r < 8; ++r) dst[(size_t)r * H_DIM] = acc[r] * scl[r] + bias;
}

// ---------------- kernel 3: fused pairwise GEMM + LN + SiLU + W2 dot ----------
// grid 2048 (b, nt, mt) x 512 threads (8 waves). Block: 64 pairs x 512 H.
// B (W1c bf16, wave's 64-h slice x K=256) lives in REGISTERS: bw[4][8] = 128 VGPRs.
// A (|t-d| bf16, 64 pairs x 256 K) staged ONCE in XOR-swizzled LDS.
// K-loop has ZERO barriers and ZERO staging: 4 ds_read_b128 + 16 MFMA per chunk.
__global__ __launch_bounds__(512, 2)
void main_kernel(const float* __restrict__ track, const float* __restrict__ det,
                 const __bf16* __restrict__ W1cc,
                 const float* __restrict__ P, const float* __restrict__ Q,
                 const float* __restrict__ gamma, const float* __restrict__ beta,
                 const float* __restrict__ W2, const float* __restrict__ b2,
                 float* __restrict__ out) {
    __shared__ float tsl[8 * TSTR];                  // 8.1 KB raw t rows (padded)
    __shared__ float dsl[8 * TSTR];                  // 8.1 KB raw d rows
    __shared__ __align__(16) __bf16 Ash[64 * 256];   // 32 KB |t-d| bf16, swizzled
    __shared__ float Psl[8 * H_DIM];                 // 16 KB
    __shared__ float Qsl[8 * H_DIM];                 // 16 KB
    __shared__ float sclT[8], sclD[8];
    __shared__ float LNr1[64][8];
    __shared__ float LNr2[64][8];
    __shared__ float MuS[64];
    __shared__ float RsS[64];
    __shared__ float Red2[64][8];

    int tid  = threadIdx.x;
    int lane = tid & 63;
    int wave = tid >> 6;
    int lq   = lane >> 4;   // quad 0..3
    int lc   = lane & 15;   // col in tile

    int blk = blockIdx.x;
    int b   = blk >> 8;
    int n0  = ((blk >> 4) & 15) * 8;
    int m0  = (blk & 15) * 8;

    // ---- issue t/d staging loads FIRST (so their waitcnt doesn't drain B loads)
    int srow = tid >> 6, sq = tid & 63;
    float4 tstage = ((const float4*)(track + (size_t)(b * 128 + n0 + srow) * E_DIM))[sq];
    float4 dstage = ((const float4*)(det   + (size_t)(b * 128 + m0 + srow) * E_DIM))[sq];

    // ---- B preload into registers: 32 x 1KB permuted-contiguous wave loads (L2)
    const uint4* Wg = (const uint4*)W1cc;   // [c][h][32bf16] => uint4 idx = c*2048 + h*4 + lq
    bf16x8 bw[4][8];
#pragma unroll
    for (int ht = 0; ht < 4; ++ht) {
        int h = wave * 64 + ht * 16 + lc;
#pragma unroll
        for (int c = 0; c < 8; ++c)
            bw[ht][c] = __builtin_bit_cast(bf16x8, Wg[c * 2048 + h * 4 + lq]);
    }

    // ---- write raw rows to LDS
    *(float4*)&tsl[srow * TSTR + sq * 4] = tstage;
    *(float4*)&dsl[srow * TSTR + sq * 4] = dstage;
    __syncthreads();

    // ---- row inverse norms: wave w -> t-row w and d-row w
    {
        float4 tv = *(const float4*)&tsl[wave * TSTR + lane * 4];
        float sst = tv.x*tv.x + tv.y*tv.y + tv.z*tv.z + tv.w*tv.w;
#pragma unroll
        for (int off = 32; off > 0; off >>= 1) sst += __shfl_xor(sst, off);
        float4 dv = *(const float4*)&dsl[wave * TSTR + lane * 4];
        float ssd = dv.x*dv.x + dv.y*dv.y + dv.z*dv.z + dv.w*dv.w;
#pragma unroll
        for (int off = 32; off > 0; off >>= 1) ssd += __shfl_xor(ssd, off);
        if (lane == 0) {
            sclT[wave] = 1.0f / fmaxf(sqrtf(sst), 1e-12f);
            sclD[wave] = 1.0f / fmaxf(sqrtf(ssd), 1e-12f);
        }
    }
    __syncthreads();

    // ---- stage A = |scl_t*t - scl_d*d| in bf16, once. thread -> (pair p, unit set)
    // unit u = i*8+j covers k = u*8..u*8+7 ; stored at slot u^(p&7)  (XOR swizzle)
    {
        int p  = tid >> 3;          // 0..63
        int j  = tid & 7;           // 0..7
        int nl = p >> 3, ml = p & 7;
        float st = sclT[nl], sd = sclD[ml];
        const float* tr = &tsl[nl * TSTR];
        const float* dr = &dsl[ml * TSTR];
#pragma unroll
        for (int i = 0; i < 4; ++i) {
            int k0 = i * 64 + j * 8;
            float4 t0 = *(const float4*)(tr + k0);
            float4 t1 = *(const float4*)(tr + k0 + 4);
            float4 d0 = *(const float4*)(dr + k0);
            float4 d1 = *(const float4*)(dr + k0 + 4);
            bf16x8 v;
            v[0] = (__bf16)fabsf(t0.x * st - d0.x * sd);
            v[1] = (__bf16)fabsf(t0.y * st - d0.y * sd);
            v[2] = (__bf16)fabsf(t0.z * st - d0.z * sd);
            v[3] = (__bf16)fabsf(t0.w * st - d0.w * sd);
            v[4] = (__bf16)fabsf(t1.x * st - d1.x * sd);
            v[5] = (__bf16)fabsf(t1.y * st - d1.y * sd);
            v[6] = (__bf16)fabsf(t1.z * st - d1.z * sd);
            v[7] = (__bf16)fabsf(t1.w * st - d1.w * sd);
            int slot = (i * 8 + j) ^ (p & 7);
            *(bf16x8*)&Ash[p * 256 + slot * 8] = v;
        }
    }
    __syncthreads();

    // ---- K-loop: no barriers, no staging
    f32x4 acc[4][4];
#pragma unroll
    for (int pt = 0; pt < 4; ++pt)
#pragma unroll
        for (int ht = 0; ht < 4; ++ht)
            acc[pt][ht] = (f32x4){0.f, 0.f, 0.f, 0.f};

#pragma unroll
    for (int c = 0; c < 8; ++c) {
        bf16x8 af[4];
#pragma unroll
        for (int pt = 0; pt < 4; ++pt) {
            int pr = pt * 16 + lc;
            int slot = ((c << 2) | lq) ^ (lc & 7);
            af[pt] = *(const bf16x8*)&Ash[pr * 256 + slot * 8];
        }
#pragma unroll
        for (int pt = 0; pt < 4; ++pt)
#pragma unroll
            for (int ht = 0; ht < 4; ++ht)
                acc[pt][ht] = __builtin_amdgcn_mfma_f32_16x16x32_bf16(af[pt], bw[ht][c], acc[pt][ht], 0, 0, 0);
    }

    // ---- stage P/Q slices to LDS (32 KB coalesced from L2), then epilogue
    {
        const float4* Pg = (const float4*)(P + (size_t)(b * 128 + n0) * H_DIM);
        const float4* Qg = (const float4*)(Q + (size_t)(b * 128 + m0) * H_DIM);
        ((float4*)Psl)[tid]       = Pg[tid];
        ((float4*)Psl)[tid + 512] = Pg[tid + 512];
        ((float4*)Qsl)[tid]       = Qg[tid];
        ((float4*)Qsl)[tid + 512] = Qg[tid + 512];
    }
    __syncthreads();

    // C/D layout: col = lc (h within tile), row = lq*4 + reg (pair within tile)
#pragma unroll
    for (int pt = 0; pt < 4; ++pt) {
#pragma unroll
        for (int rg = 0; rg < 4; ++rg) {
            int p = pt * 16 + lq * 4 + rg;
            const float* Pr = &Psl[(p >> 3) * H_DIM];
            const float* Qr = &Qsl[(p & 7) * H_DIM];
#pragma unroll
            for (int ht = 0; ht < 4; ++ht) {
                int h = wave * 64 + ht * 16 + lc;
                acc[pt][ht][rg] += Pr[h] + Qr[h];
            }
        }
    }

    // LayerNorm partial sums (per pair, this wave's 64 h-values)
#pragma unroll
    for (int pt = 0; pt < 4; ++pt) {
#pragma unroll
        for (int rg = 0; rg < 4; ++rg) {
            float s1 = 0.f, s2 = 0.f;
#pragma unroll
            for (int ht = 0; ht < 4; ++ht) {
                float v = acc[pt][ht][rg];
                s1 += v; s2 += v * v;
            }
#pragma unroll
            for (int off = 1; off < 16; off <<= 1) {
                s1 += __shfl_xor(s1, off);
                s2 += __shfl_xor(s2, off);
            }
            if (lc == 0) {
                int p = pt * 16 + lq * 4 + rg;
                LNr1[p][wave] = s1;
                LNr2[p][wave] = s2;
            }
        }
    }
    __syncthreads();
    if (tid < 64) {
        float S1 = 0.f, S2 = 0.f;
#pragma unroll
        for (int w = 0; w < 8; ++w) { S1 += LNr1[tid][w]; S2 += LNr2[tid][w]; }
        float mu = S1 * (1.0f / 512.0f);
        float var = S2 * (1.0f / 512.0f) - mu * mu;
        MuS[tid] = mu;
        RsS[tid] = rsqrtf(var + 1e-5f);
    }
    __syncthreads();

    float gv[4], bv[4], wv[4];
#pragma unroll
    for (int ht = 0; ht < 4; ++ht) {
        int h = wave * 64 + ht * 16 + lc;
        gv[ht] = gamma[h];
        bv[ht] = beta[h];
        wv[ht] = W2[h];
    }
#pragma unroll
    for (int pt = 0; pt < 4; ++pt) {
#pragma unroll
        for (int rg = 0; rg < 4; ++rg) {
            int p = pt * 16 + lq * 4 + rg;
            float mu = MuS[p], rs = RsS[p];
            float ca = 0.f;
#pragma unroll
            for (int ht = 0; ht < 4; ++ht) {
                float x = (acc[pt][ht][rg] - mu) * rs * gv[ht] + bv[ht];
                float sg = 1.0f / (1.0f + __expf(-x));
                ca += (x * sg) * wv[ht];
            }
#pragma unroll
            for (int off = 1; off < 16; off <<= 1) ca += __shfl_xor(ca, off);
            if (lc == 0) Red2[p][wave] = ca;
        }
    }
    __syncthreads();
    if (tid < 64) {
        float o = b2[0];
#pragma unroll
        for (int w = 0; w < 8; ++w) o += Red2[tid][w];
        int n = n0 + (tid >> 3);
        int m = m0 + (tid & 7);
        out[(size_t)(b * 128 + n) * 128 + m] = o;
    }
}

extern "C" void kernel_launch(void* const* d_in, const int* in_sizes, int n_in,
                              void* d_out, int out_size, void* d_ws, size_t ws_size,
                              hipStream_t stream) {
    const float* track = (const float*)d_in[0];
    const float* det   = (const float*)d_in[1];
    const float* W1    = (const float*)d_in[2];
    const float* b1    = (const float*)d_in[3];
    const float* gamma = (const float*)d_in[4];
    const float* beta  = (const float*)d_in[5];
    const float* W2    = (const float*)d_in[6];
    const float* b2    = (const float*)d_in[7];
    float* out = (float*)d_out;

    char* ws = (char*)d_ws;
    float*  P     = (float*)(ws);                      // 2 MB  (1024 x 512 f32)
    float*  Q     = (float*)(ws + (2u << 20));         // 2 MB
    __bf16* W1cc  = (__bf16*)(ws + (4u << 20));        // 256 KB (bf16, chunk-major)

    w1c_kernel<<<512, 256, 0, stream>>>(W1, W1cc);
    pq_kernel<<<256, 512, 0, stream>>>(track, det, W1, b1, P, Q);
    main_kernel<<<2048, 512, 0, stream>>>(track, det, W1cc, P, Q, gamma, beta, W2, b2, out);
}

// Round 3
// 181.090 us; speedup vs baseline: 1.2781x; 1.2781x over previous
//
#include <hip/hip_runtime.h>
#include <hip/hip_bf16.h>
#include <cstdint>

typedef __bf16 bf16x8 __attribute__((ext_vector_type(8)));
typedef float f32x4 __attribute__((ext_vector_type(4)));

#define E_DIM 256
#define H_DIM 512
#define TSTR 260   // padded f32 row stride (260*4B; %16B==0 so float4 rows stay aligned)

// ================= prep kernel: w1c transpose (blocks 0..63) + P/Q GEMM (64..575) =================
// w1c: W1cc[c*16384 + h*32 + kk] = bf16(W1[(512 + c*32 + kk)*512 + h]), coalesced 16B writes.
// pq : P = norm(t)@W1a + b1 ; Q = norm(d)@W1b (f32). Block = 8 rows x 256 h-half. 256 thr.
__global__ __launch_bounds__(256)
void prep_kernel(const float* __restrict__ track, const float* __restrict__ det,
                 const float* __restrict__ W1, const float* __restrict__ b1,
                 float* __restrict__ P, float* __restrict__ Q,
                 __bf16* __restrict__ W1cc) {
    int blk = blockIdx.x;
    int tid = threadIdx.x;

    if (blk < 64) {
        // ---- w1c part: 16384 bf16x8 units
        int u = blk * 256 + tid;
        int j = u & 3;            // kk-oct
        int h = (u >> 2) & 511;
        int c = u >> 11;
        bf16x8 v;
#pragma unroll
        for (int i = 0; i < 8; ++i)
            v[i] = (__bf16)W1[(size_t)(512 + c * 32 + j * 8 + i) * H_DIM + h];
        *(bf16x8*)(W1cc + (size_t)c * 16384 + (size_t)h * 32 + j * 8) = v;
        return;
    }

    // ---- pq part
    __shared__ float xs[8 * E_DIM];   // 8 KB
    __shared__ float scl[8];
    int q      = blk - 64;
    int rowgrp = q >> 2;
    int mat    = (q >> 1) & 1;        // 0 = P(track), 1 = Q(det)
    int half   = q & 1;
    int r0     = rowgrp * 8;
    const float* src = mat ? det : track;

    // stage 8 rows x 256 f32 (wave w holds rows w and w+4 in regs)
    float4 s0 = ((const float4*)(src + (size_t)r0 * E_DIM))[tid];
    float4 s1 = ((const float4*)(src + (size_t)r0 * E_DIM))[tid + 256];
    ((float4*)xs)[tid]       = s0;
    ((float4*)xs)[tid + 256] = s1;

    {   // row norms from registers: wave w reduces rows w (s0) and w+4 (s1)
        int w = tid >> 6, lane = tid & 63;
        float a = s0.x*s0.x + s0.y*s0.y + s0.z*s0.z + s0.w*s0.w;
        float b = s1.x*s1.x + s1.y*s1.y + s1.z*s1.z + s1.w*s1.w;
#pragma unroll
        for (int off = 32; off > 0; off >>= 1) { a += __shfl_xor(a, off); b += __shfl_xor(b, off); }
        if (lane == 0) {
            scl[w]     = 1.0f / fmaxf(sqrtf(a), 1e-12f);
            scl[w + 4] = 1.0f / fmaxf(sqrtf(b), 1e-12f);
        }
    }
    __syncthreads();

    int h = half * 256 + tid;         // global h for this thread
    const float* wcol = W1 + (size_t)mat * (E_DIM * H_DIM) + h;
    float acc[8];
#pragma unroll
    for (int r = 0; r < 8; ++r) acc[r] = 0.0f;
#pragma unroll 2
    for (int e0 = 0; e0 < E_DIM; e0 += 4) {
        float w0 = wcol[(size_t)(e0 + 0) * H_DIM];
        float w1v = wcol[(size_t)(e0 + 1) * H_DIM];
        float w2v = wcol[(size_t)(e0 + 2) * H_DIM];
        float w3v = wcol[(size_t)(e0 + 3) * H_DIM];
#pragma unroll
        for (int r = 0; r < 8; ++r) {
            const float* xr = xs + r * E_DIM + e0;
            acc[r] += xr[0] * w0 + xr[1] * w1v + xr[2] * w2v + xr[3] * w3v;
        }
    }
    float bias = mat ? 0.0f : b1[h];
    float* dst = (mat ? Q : P) + (size_t)r0 * H_DIM + h;
#pragma unroll
    for (int r = 0; r < 8; ++r) dst[(size_t)r * H_DIM] = acc[r] * scl[r] + bias;
}

// ================= main kernel: pairwise GEMM + LN + SiLU + W2 dot =================
// grid 2048 (b, nt, mt) x 512 threads (8 waves). Block: 64 pairs x 512 H; K=256 in 8 chunks.
// B (wave's 64-h slice) register double-buffered (32 VGPRs). A staged once in LDS with a
// layout where BOTH stage-write and frag-read are uniform_base + lane*16 (conflict-free).
// LDS arena is phase-overlaid: Ash(32K) -> Psl/Qsl(32K); tsl(8.3K) -> LN scratch.
__global__ __launch_bounds__(512, 4)
void main_kernel(const float* __restrict__ track, const float* __restrict__ det,
                 const __bf16* __restrict__ W1cc,
                 const float* __restrict__ P, const float* __restrict__ Q,
                 const float* __restrict__ gamma, const float* __restrict__ beta,
                 const float* __restrict__ W2, const float* __restrict__ b2,
                 float* __restrict__ out) {
    __shared__ __align__(16) char SMEM[49408];
    __bf16* Ash = (__bf16*)SMEM;                       // [0,32768) phase 1
    float*  Psl = (float*)SMEM;                        // [0,16384) phase 2
    float*  Qsl = (float*)(SMEM + 16384);              // [16384,32768) phase 2
    float*  tsl = (float*)(SMEM + 32768);              // [32768,41088) phase 1 (8*TSTR f32)
    float*  dsl = (float*)(SMEM + 41088);              // [41088,49408) phase 1
    float*  LNr1 = (float*)(SMEM + 32768);             // [64][8] phase 2
    float*  LNr2 = (float*)(SMEM + 34816);             // [64][8]
    float*  Red2 = (float*)(SMEM + 36864);             // [64][8]
    float*  MuS  = (float*)(SMEM + 38912);             // [64]
    float*  RsS  = (float*)(SMEM + 39168);             // [64]
    __shared__ float sclT[8], sclD[8];

    int tid  = threadIdx.x;
    int lane = tid & 63;
    int wave = tid >> 6;
    int lq   = lane >> 4;   // quad 0..3
    int lc   = lane & 15;

    int blk = blockIdx.x;
    int b   = blk >> 8;
    int n0  = ((blk >> 4) & 15) * 8;
    int m0  = (blk & 15) * 8;

    // ---- stage loads: wave w holds row w of the t-slice and d-slice
    float4 tstage = ((const float4*)(track + (size_t)(b * 128 + n0 + wave) * E_DIM))[lane];
    float4 dstage = ((const float4*)(det   + (size_t)(b * 128 + m0 + wave) * E_DIM))[lane];

    // ---- B prefetch chunk 0 (L2-resident W1cc; 1 KB contiguous per instr)
    const uint4* Wg = (const uint4*)W1cc;   // [c][h][32 bf16] -> uint4 idx = c*2048 + h*4 + lq
    int hb = wave * 64 + lc;
    bf16x8 bwA[4], bwB[4];
#pragma unroll
    for (int ht = 0; ht < 4; ++ht)
        bwA[ht] = __builtin_bit_cast(bf16x8, Wg[(hb + ht * 16) * 4 + lq]);

    // ---- row norms from registers (no extra barrier)
    {
        float a = tstage.x*tstage.x + tstage.y*tstage.y + tstage.z*tstage.z + tstage.w*tstage.w;
        float d = dstage.x*dstage.x + dstage.y*dstage.y + dstage.z*dstage.z + dstage.w*dstage.w;
#pragma unroll
        for (int off = 32; off > 0; off >>= 1) { a += __shfl_xor(a, off); d += __shfl_xor(d, off); }
        if (lane == 0) {
            sclT[wave] = 1.0f / fmaxf(sqrtf(a), 1e-12f);
            sclD[wave] = 1.0f / fmaxf(sqrtf(d), 1e-12f);
        }
    }
    *(float4*)&tsl[wave * TSTR + lane * 4] = tstage;
    *(float4*)&dsl[wave * TSTR + lane * 4] = dstage;
    __syncthreads();

    // ---- A-stage: iteration r: lane covers pair p = r*16 + lc, k = wave*32 + lq*8 .. +7
    // storage chunk index a16 = r*512 + wave*64 + lane  ==> read side ((pt*8+c)*64 + lane)
    {
        int k0 = wave * 32 + lq * 8;
        int ml = lane & 7;
        float sd = sclD[ml];
        const float* dr = dsl + ml * TSTR + k0;
        float4 d0 = *(const float4*)dr;
        float4 d1 = *(const float4*)(dr + 4);
#pragma unroll
        for (int r = 0; r < 4; ++r) {
            int nl = r * 2 + (lc >> 3);
            float st = sclT[nl];
            const float* tr = tsl + nl * TSTR + k0;
            float4 t0 = *(const float4*)tr;
            float4 t1 = *(const float4*)(tr + 4);
            bf16x8 v;
            v[0] = (__bf16)fabsf(t0.x * st - d0.x * sd);
            v[1] = (__bf16)fabsf(t0.y * st - d0.y * sd);
            v[2] = (__bf16)fabsf(t0.z * st - d0.z * sd);
            v[3] = (__bf16)fabsf(t0.w * st - d0.w * sd);
            v[4] = (__bf16)fabsf(t1.x * st - d1.x * sd);
            v[5] = (__bf16)fabsf(t1.y * st - d1.y * sd);
            v[6] = (__bf16)fabsf(t1.z * st - d1.z * sd);
            v[7] = (__bf16)fabsf(t1.w * st - d1.w * sd);
            *(bf16x8*)&Ash[(size_t)(r * 512 + wave * 64 + lane) * 8] = v;
        }
    }
    __syncthreads();

    // ---- K-loop: zero barriers; B double-buffered in regs; A reads base+lane*16
    f32x4 acc[4][4];
#pragma unroll
    for (int pt = 0; pt < 4; ++pt)
#pragma unroll
        for (int ht = 0; ht < 4; ++ht)
            acc[pt][ht] = (f32x4){0.f, 0.f, 0.f, 0.f};

#pragma unroll
    for (int c = 0; c < 8; ++c) {
        bf16x8* cur = (c & 1) ? bwB : bwA;
        bf16x8* nxt = (c & 1) ? bwA : bwB;
        if (c < 7) {
#pragma unroll
            for (int ht = 0; ht < 4; ++ht)
                nxt[ht] = __builtin_bit_cast(bf16x8, Wg[(c + 1) * 2048 + (hb + ht * 16) * 4 + lq]);
        }
#pragma unroll
        for (int pt = 0; pt < 4; ++pt) {
            bf16x8 af = *(const bf16x8*)&Ash[(size_t)((pt * 8 + c) * 64 + lane) * 8];
#pragma unroll
            for (int ht = 0; ht < 4; ++ht)
                acc[pt][ht] = __builtin_amdgcn_mfma_f32_16x16x32_bf16(af, cur[ht], acc[pt][ht], 0, 0, 0);
        }
    }
    __syncthreads();   // Ash dead; reuse as Psl/Qsl

    // ---- stage P/Q slices (coalesced 16 KB each)
    {
        const float4* Pg = (const float4*)(P + (size_t)(b * 128 + n0) * H_DIM);
        const float4* Qg = (const float4*)(Q + (size_t)(b * 128 + m0) * H_DIM);
        ((float4*)Psl)[tid]       = Pg[tid];
        ((float4*)Psl)[tid + 512] = Pg[tid + 512];
        ((float4*)Qsl)[tid]       = Qg[tid];
        ((float4*)Qsl)[tid + 512] = Qg[tid + 512];
    }
    __syncthreads();

    // ---- acc += P + Q ; LN partial sums
#pragma unroll
    for (int pt = 0; pt < 4; ++pt) {
#pragma unroll
        for (int rg = 0; rg < 4; ++rg) {
            int p = pt * 16 + lq * 4 + rg;
            const float* Pr = &Psl[(p >> 3) * H_DIM];
            const float* Qr = &Qsl[(p & 7) * H_DIM];
            float s1 = 0.f, s2 = 0.f;
#pragma unroll
            for (int ht = 0; ht < 4; ++ht) {
                int h = wave * 64 + ht * 16 + lc;
                float v = acc[pt][ht][rg] + Pr[h] + Qr[h];
                acc[pt][ht][rg] = v;
                s1 += v; s2 += v * v;
            }
#pragma unroll
            for (int off = 1; off < 16; off <<= 1) {
                s1 += __shfl_xor(s1, off);
                s2 += __shfl_xor(s2, off);
            }
            if (lc == 0) {
                LNr1[p * 8 + wave] = s1;
                LNr2[p * 8 + wave] = s2;
            }
        }
    }
    __syncthreads();
    if (tid < 64) {
        float S1 = 0.f, S2 = 0.f;
#pragma unroll
        for (int w = 0; w < 8; ++w) { S1 += LNr1[tid * 8 + w]; S2 += LNr2[tid * 8 + w]; }
        float mu = S1 * (1.0f / 512.0f);
        float var = S2 * (1.0f / 512.0f) - mu * mu;
        MuS[tid] = mu;
        RsS[tid] = rsqrtf(var + 1e-5f);
    }
    __syncthreads();

    // ---- normalize + SiLU + W2 partial dot
    float gv[4], bv[4], wv[4];
#pragma unroll
    for (int ht = 0; ht < 4; ++ht) {
        int h = wave * 64 + ht * 16 + lc;
        gv[ht] = gamma[h];
        bv[ht] = beta[h];
        wv[ht] = W2[h];
    }
#pragma unroll
    for (int pt = 0; pt < 4; ++pt) {
#pragma unroll
        for (int rg = 0; rg < 4; ++rg) {
            int p = pt * 16 + lq * 4 + rg;
            float mu = MuS[p], rs = RsS[p];
            float ca = 0.f;
#pragma unroll
            for (int ht = 0; ht < 4; ++ht) {
                float x = (acc[pt][ht][rg] - mu) * rs * gv[ht] + bv[ht];
                float sg = 1.0f / (1.0f + __expf(-x));
                ca += (x * sg) * wv[ht];
            }
#pragma unroll
            for (int off = 1; off < 16; off <<= 1) ca += __shfl_xor(ca, off);
            if (lc == 0) Red2[p * 8 + wave] = ca;
        }
    }
    __syncthreads();
    if (tid < 64) {
        float o = b2[0];
#pragma unroll
        for (int w = 0; w < 8; ++w) o += Red2[tid * 8 + w];
        int n = n0 + (tid >> 3);
        int m = m0 + (tid & 7);
        out[(size_t)(b * 128 + n) * 128 + m] = o;
    }
}

extern "C" void kernel_launch(void* const* d_in, const int* in_sizes, int n_in,
                              void* d_out, int out_size, void* d_ws, size_t ws_size,
                              hipStream_t stream) {
    const float* track = (const float*)d_in[0];
    const float* det   = (const float*)d_in[1];
    const float* W1    = (const float*)d_in[2];
    const float* b1    = (const float*)d_in[3];
    const float* gamma = (const float*)d_in[4];
    const float* beta  = (const float*)d_in[5];
    const float* W2    = (const float*)d_in[6];
    const float* b2    = (const float*)d_in[7];
    float* out = (float*)d_out;

    char* ws = (char*)d_ws;
    float*  P     = (float*)(ws);                      // 2 MB  (1024 x 512 f32)
    float*  Q     = (float*)(ws + (2u << 20));         // 2 MB
    __bf16* W1cc  = (__bf16*)(ws + (4u << 20));        // 256 KB (bf16, chunk-major)

    prep_kernel<<<576, 256, 0, stream>>>(track, det, W1, b1, P, Q, W1cc);
    main_kernel<<<2048, 512, 0, stream>>>(track, det, W1cc, P, Q, gamma, beta, W2, b2, out);
}

// Round 4
// 172.546 us; speedup vs baseline: 1.3414x; 1.0495x over previous
//
#include <hip/hip_runtime.h>
#include <hip/hip_bf16.h>
#include <cstdint>

typedef __bf16 bf16x8 __attribute__((ext_vector_type(8)));
typedef float f32x4 __attribute__((ext_vector_type(4)));

#define E_DIM 256
#define H_DIM 512
#define TSTR 260   // padded f32 row stride (1040 B: 16B-aligned rows, odd 16B-groups)

// ---------------- kernel 1: W1 (all 3 blocks) -> bf16 chunk-major [mat][c][h][kk] ----------------
__global__ __launch_bounds__(256)
void w1conv_kernel(const float* __restrict__ W1, __bf16* __restrict__ W1cc) {
    int u = blockIdx.x * 256 + threadIdx.x;   // 0..49151
    int j   = u & 3;
    int h   = (u >> 2) & 511;
    int c   = (u >> 11) & 7;
    int mat = u >> 14;                        // 0..2
    bf16x8 v;
#pragma unroll
    for (int i = 0; i < 8; ++i)
        v[i] = (__bf16)W1[(size_t)(mat * 256 + c * 32 + j * 8 + i) * H_DIM + h];
    *(bf16x8*)(W1cc + ((size_t)(mat * 8 + c) * 512 + h) * 32 + j * 8) = v;
}

// ---------------- kernel 2: P = norm(t)@W1a + b1 ; Q = norm(d)@W1b via bf16 MFMA ----------------
// 32 blocks x 512 thr. Block = 64 rows x 512 h. C layout [h x row] (A = W-frags, B = row-frags).
__global__ __launch_bounds__(512, 4)
void pq_mfma_kernel(const float* __restrict__ track, const float* __restrict__ det,
                    const __bf16* __restrict__ W1cc, const float* __restrict__ b1,
                    float* __restrict__ P, float* __restrict__ Q) {
    __shared__ __align__(16) __bf16 Ash[64 * 256];   // 32 KB
    __shared__ float sclS[64];

    int tid  = threadIdx.x;
    int lane = tid & 63;
    int wave = tid >> 6;
    int lq   = lane >> 4;
    int lc   = lane & 15;

    int blk = blockIdx.x;
    bool isP = blk < 16;
    int r0 = (blk & 15) * 64;
    const float* src = isP ? track : det;

    // ---- row norms: wave w handles rows w*8 .. w*8+7
#pragma unroll
    for (int i = 0; i < 8; ++i) {
        int row = wave * 8 + i;
        float4 x = ((const float4*)(src + (size_t)(r0 + row) * E_DIM))[lane];
        float ss = x.x*x.x + x.y*x.y + x.z*x.z + x.w*x.w;
#pragma unroll
        for (int off = 32; off > 0; off >>= 1) ss += __shfl_xor(ss, off);
        if (lane == 0) sclS[row] = 1.0f / fmaxf(sqrtf(ss), 1e-12f);
    }
    __syncthreads();

    // ---- A-stage from global, scaled, bf16
#pragma unroll
    for (int r = 0; r < 4; ++r) {
        int row = r * 16 + lc;
        float st = sclS[row];
        const float* gp = src + (size_t)(r0 + row) * E_DIM + wave * 32 + lq * 8;
        float4 t0 = *(const float4*)gp;
        float4 t1 = *(const float4*)(gp + 4);
        bf16x8 v;
        v[0] = (__bf16)(t0.x * st); v[1] = (__bf16)(t0.y * st);
        v[2] = (__bf16)(t0.z * st); v[3] = (__bf16)(t0.w * st);
        v[4] = (__bf16)(t1.x * st); v[5] = (__bf16)(t1.y * st);
        v[6] = (__bf16)(t1.z * st); v[7] = (__bf16)(t1.w * st);
        *(bf16x8*)&Ash[(size_t)(r * 512 + wave * 64 + lane) * 8] = v;
    }
    __syncthreads();

    // ---- B = W1a or W1b frags (register dbuf); frag h = wave*64 + ht*16 + lc
    const uint4* Wg = (const uint4*)W1cc + (isP ? 0 : 16384);
    int hb = wave * 64 + lc;
    bf16x8 bwA[4], bwB[4];
#pragma unroll
    for (int ht = 0; ht < 4; ++ht)
        bwA[ht] = __builtin_bit_cast(bf16x8, Wg[(hb + ht * 16) * 4 + lq]);

    f32x4 acc[4][4];
#pragma unroll
    for (int pt = 0; pt < 4; ++pt)
#pragma unroll
        for (int ht = 0; ht < 4; ++ht)
            acc[pt][ht] = (f32x4){0.f, 0.f, 0.f, 0.f};

#pragma unroll
    for (int c = 0; c < 8; ++c) {
        bf16x8* cur = (c & 1) ? bwB : bwA;
        bf16x8* nxt = (c & 1) ? bwA : bwB;
        if (c < 7) {
#pragma unroll
            for (int ht = 0; ht < 4; ++ht)
                nxt[ht] = __builtin_bit_cast(bf16x8, Wg[(c + 1) * 2048 + (hb + ht * 16) * 4 + lq]);
        }
#pragma unroll
        for (int pt = 0; pt < 4; ++pt) {
            bf16x8 af = *(const bf16x8*)&Ash[(size_t)((pt * 8 + c) * 64 + lane) * 8];
#pragma unroll
            for (int ht = 0; ht < 4; ++ht)
                acc[pt][ht] = __builtin_amdgcn_mfma_f32_16x16x32_bf16(cur[ht], af, acc[pt][ht], 0, 0, 0);
        }
    }

    // ---- store (+bias for P). Element: row = r0 + pt*16+lc, h = wave*64+ht*16+lq*4+rg
    float* dst = isP ? P : Q;
#pragma unroll
    for (int ht = 0; ht < 4; ++ht) {
        int h = wave * 64 + ht * 16 + lq * 4;
        f32x4 bvv = (f32x4){0.f, 0.f, 0.f, 0.f};
        if (isP) bvv = *(const f32x4*)&b1[h];
#pragma unroll
        for (int pt = 0; pt < 4; ++pt) {
            f32x4 o = acc[pt][ht] + bvv;
            *(f32x4*)&dst[(size_t)(r0 + pt * 16 + lc) * H_DIM + h] = o;
        }
    }
}

// ---------------- kernel 3: fused pairwise GEMM + LN + SiLU + W2 dot ----------------
// grid 2048 x 512 thr (8 waves). Block: 64 pairs x 512 H; K=256, 8 chunks.
// C layout [h x pair]: A = W1c frags (register dbuf), B = |t-d| frags from LDS.
// Element: pair = pt*16+lc (n=pt*2+(lc>>3), m=lc&7); h = wave*64+ht*16+lq*4+rg.
__global__ __launch_bounds__(512, 4)
void main_kernel(const float* __restrict__ track, const float* __restrict__ det,
                 const __bf16* __restrict__ W1cc,
                 const float* __restrict__ P, const float* __restrict__ Q,
                 const float* __restrict__ gamma, const float* __restrict__ beta,
                 const float* __restrict__ W2, const float* __restrict__ b2,
                 float* __restrict__ out) {
    __shared__ __align__(16) char SMEM[49408];
    __bf16* Ash  = (__bf16*)SMEM;                     // [0,32768) phase 1+2
    float*  tsl  = (float*)(SMEM + 32768);            // 8*TSTR f32, phase 1
    float*  dsl  = (float*)(SMEM + 41088);            // phase 1
    float*  LNr1 = (float*)(SMEM + 32768);            // [64][9] phase 2 (tsl dead)
    float*  LNr2 = (float*)(SMEM + 35072);            // [64][9]
    float*  Red2 = (float*)(SMEM + 37376);            // [64][9]
    float*  MuS  = (float*)(SMEM + 39680);            // [64]
    float*  RsS  = (float*)(SMEM + 39936);            // [64]
    __shared__ float sclT[8], sclD[8];

    int tid  = threadIdx.x;
    int lane = tid & 63;
    int wave = tid >> 6;
    int lq   = lane >> 4;
    int lc   = lane & 15;

    int blk = blockIdx.x;
    int b   = blk >> 8;
    int n0  = ((blk >> 4) & 15) * 8;
    int m0  = (blk & 15) * 8;

    // ---- stage loads: wave w holds row w of t-slice and d-slice
    float4 tstage = ((const float4*)(track + (size_t)(b * 128 + n0 + wave) * E_DIM))[lane];
    float4 dstage = ((const float4*)(det   + (size_t)(b * 128 + m0 + wave) * E_DIM))[lane];

    // ---- W1c frags, chunk-0 prefetch (mat 2 base = 32768 uint4)
    const uint4* Wg = (const uint4*)W1cc + 32768;
    int hb = wave * 64 + lc;
    bf16x8 bwA[4], bwB[4];
#pragma unroll
    for (int ht = 0; ht < 4; ++ht)
        bwA[ht] = __builtin_bit_cast(bf16x8, Wg[(hb + ht * 16) * 4 + lq]);

    // ---- row norms from registers
    {
        float a = tstage.x*tstage.x + tstage.y*tstage.y + tstage.z*tstage.z + tstage.w*tstage.w;
        float d = dstage.x*dstage.x + dstage.y*dstage.y + dstage.z*dstage.z + dstage.w*dstage.w;
#pragma unroll
        for (int off = 32; off > 0; off >>= 1) { a += __shfl_xor(a, off); d += __shfl_xor(d, off); }
        if (lane == 0) {
            sclT[wave] = 1.0f / fmaxf(sqrtf(a), 1e-12f);
            sclD[wave] = 1.0f / fmaxf(sqrtf(d), 1e-12f);
        }
    }
    *(float4*)&tsl[wave * TSTR + lane * 4] = tstage;
    *(float4*)&dsl[wave * TSTR + lane * 4] = dstage;
    __syncthreads();

    // ---- A-stage: iter r covers pair p = r*16+lc, k = wave*32+lq*8 .. +7
    {
        int k0 = wave * 32 + lq * 8;
        int ml = lane & 7;
        float sd = sclD[ml];
        const float* dr = dsl + ml * TSTR + k0;
        float4 d0 = *(const float4*)dr;
        float4 d1 = *(const float4*)(dr + 4);
#pragma unroll
        for (int r = 0; r < 4; ++r) {
            int nl = r * 2 + (lc >> 3);
            float st = sclT[nl];
            const float* tr = tsl + nl * TSTR + k0;
            float4 t0 = *(const float4*)tr;
            float4 t1 = *(const float4*)(tr + 4);
            bf16x8 v;
            v[0] = (__bf16)fabsf(t0.x * st - d0.x * sd);
            v[1] = (__bf16)fabsf(t0.y * st - d0.y * sd);
            v[2] = (__bf16)fabsf(t0.z * st - d0.z * sd);
            v[3] = (__bf16)fabsf(t0.w * st - d0.w * sd);
            v[4] = (__bf16)fabsf(t1.x * st - d1.x * sd);
            v[5] = (__bf16)fabsf(t1.y * st - d1.y * sd);
            v[6] = (__bf16)fabsf(t1.z * st - d1.z * sd);
            v[7] = (__bf16)fabsf(t1.w * st - d1.w * sd);
            *(bf16x8*)&Ash[(size_t)(r * 512 + wave * 64 + lane) * 8] = v;
        }
    }
    __syncthreads();

    // ---- K-loop: zero barriers; W1c frags dbuf'd in regs; A reads base+lane*16
    f32x4 acc[4][4];
#pragma unroll
    for (int pt = 0; pt < 4; ++pt)
#pragma unroll
        for (int ht = 0; ht < 4; ++ht)
            acc[pt][ht] = (f32x4){0.f, 0.f, 0.f, 0.f};

#pragma unroll
    for (int c = 0; c < 8; ++c) {
        bf16x8* cur = (c & 1) ? bwB : bwA;
        bf16x8* nxt = (c & 1) ? bwA : bwB;
        if (c < 7) {
#pragma unroll
            for (int ht = 0; ht < 4; ++ht)
                nxt[ht] = __builtin_bit_cast(bf16x8, Wg[(c + 1) * 2048 + (hb + ht * 16) * 4 + lq]);
        }
#pragma unroll
        for (int pt = 0; pt < 4; ++pt) {
            bf16x8 af = *(const bf16x8*)&Ash[(size_t)((pt * 8 + c) * 64 + lane) * 8];
#pragma unroll
            for (int ht = 0; ht < 4; ++ht)
                acc[pt][ht] = __builtin_amdgcn_mfma_f32_16x16x32_bf16(cur[ht], af, acc[pt][ht], 0, 0, 0);
        }
    }

    // ---- P/Q add straight from global (L2-resident): vector f32x4
    const float* Pb = P + (size_t)(b * 128 + n0) * H_DIM;
    const float* Qb = Q + (size_t)(b * 128 + m0) * H_DIM;
    f32x4 qv[4];
#pragma unroll
    for (int ht = 0; ht < 4; ++ht)
        qv[ht] = *(const f32x4*)&Qb[(size_t)(lc & 7) * H_DIM + wave * 64 + ht * 16 + lq * 4];
#pragma unroll
    for (int pt = 0; pt < 4; ++pt) {
        int n = pt * 2 + (lc >> 3);
#pragma unroll
        for (int ht = 0; ht < 4; ++ht) {
            f32x4 pv = *(const f32x4*)&Pb[(size_t)n * H_DIM + wave * 64 + ht * 16 + lq * 4];
            acc[pt][ht] += pv + qv[ht];
        }
    }

    // ---- LN partials: in-register sum over 16 h-values, then 2-shuffle across lq
#pragma unroll
    for (int pt = 0; pt < 4; ++pt) {
        float s1 = 0.f, s2 = 0.f;
#pragma unroll
        for (int ht = 0; ht < 4; ++ht)
#pragma unroll
            for (int rg = 0; rg < 4; ++rg) {
                float v = acc[pt][ht][rg];
                s1 += v; s2 += v * v;
            }
        s1 += __shfl_xor(s1, 16); s2 += __shfl_xor(s2, 16);
        s1 += __shfl_xor(s1, 32); s2 += __shfl_xor(s2, 32);
        if (lq == 0) {
            LNr1[(pt * 16 + lc) * 9 + wave] = s1;
            LNr2[(pt * 16 + lc) * 9 + wave] = s2;
        }
    }
    __syncthreads();
    if (tid < 64) {
        float S1 = 0.f, S2 = 0.f;
#pragma unroll
        for (int w = 0; w < 8; ++w) { S1 += LNr1[tid * 9 + w]; S2 += LNr2[tid * 9 + w]; }
        float mu = S1 * (1.0f / 512.0f);
        float var = S2 * (1.0f / 512.0f) - mu * mu;
        MuS[tid] = mu;
        RsS[tid] = rsqrtf(var + 1e-5f);
    }
    __syncthreads();

    // ---- normalize + SiLU + W2 partial dot (vector param loads)
    f32x4 gvv[4], bvv[4], wvv[4];
#pragma unroll
    for (int ht = 0; ht < 4; ++ht) {
        int h = wave * 64 + ht * 16 + lq * 4;
        gvv[ht] = *(const f32x4*)&gamma[h];
        bvv[ht] = *(const f32x4*)&beta[h];
        wvv[ht] = *(const f32x4*)&W2[h];
    }
#pragma unroll
    for (int pt = 0; pt < 4; ++pt) {
        int pr = pt * 16 + lc;
        float mu = MuS[pr], rs = RsS[pr];
        float ca = 0.f;
#pragma unroll
        for (int ht = 0; ht < 4; ++ht)
#pragma unroll
            for (int rg = 0; rg < 4; ++rg) {
                float x = (acc[pt][ht][rg] - mu) * rs * gvv[ht][rg] + bvv[ht][rg];
                float sg = __builtin_amdgcn_rcpf(1.0f + __expf(-x));
                ca += x * sg * wvv[ht][rg];
            }
        ca += __shfl_xor(ca, 16);
        ca += __shfl_xor(ca, 32);
        if (lq == 0) Red2[pr * 9 + wave] = ca;
    }
    __syncthreads();
    if (tid < 64) {
        float o = b2[0];
#pragma unroll
        for (int w = 0; w < 8; ++w) o += Red2[tid * 9 + w];
        int n = n0 + (tid >> 3);
        int m = m0 + (tid & 7);
        out[(size_t)(b * 128 + n) * 128 + m] = o;
    }
}

extern "C" void kernel_launch(void* const* d_in, const int* in_sizes, int n_in,
                              void* d_out, int out_size, void* d_ws, size_t ws_size,
                              hipStream_t stream) {
    const float* track = (const float*)d_in[0];
    const float* det   = (const float*)d_in[1];
    const float* W1    = (const float*)d_in[2];
    const float* b1    = (const float*)d_in[3];
    const float* gamma = (const float*)d_in[4];
    const float* beta  = (const float*)d_in[5];
    const float* W2    = (const float*)d_in[6];
    const float* b2    = (const float*)d_in[7];
    float* out = (float*)d_out;

    char* ws = (char*)d_ws;
    float*  P     = (float*)(ws);                      // 2 MB  (1024 x 512 f32)
    float*  Q     = (float*)(ws + (2u << 20));         // 2 MB
    __bf16* W1cc  = (__bf16*)(ws + (4u << 20));        // 768 KB (bf16 chunk-major, 3 mats)

    w1conv_kernel<<<192, 256, 0, stream>>>(W1, W1cc);
    pq_mfma_kernel<<<32, 512, 0, stream>>>(track, det, W1cc, b1, P, Q);
    main_kernel<<<2048, 512, 0, stream>>>(track, det, W1cc, P, Q, gamma, beta, W2, b2, out);
}

// Round 5
// 163.902 us; speedup vs baseline: 1.4121x; 1.0527x over previous
//
#include <hip/hip_runtime.h>
#include <hip/hip_bf16.h>
#include <cstdint>

typedef __bf16 bf16x8 __attribute__((ext_vector_type(8)));
typedef float f32x4 __attribute__((ext_vector_type(4)));

#define E_DIM 256
#define H_DIM 512
#define TSTR 260   // padded f32 row stride (1040 B: 16B-aligned rows, odd 16B-groups)

// ---------------- kernel 1: W1 (all 3 blocks) -> bf16 chunk-major [mat][c][h][kk] ----------------
__global__ __launch_bounds__(256)
void w1conv_kernel(const float* __restrict__ W1, __bf16* __restrict__ W1cc) {
    int u = blockIdx.x * 256 + threadIdx.x;   // 0..49151
    int j   = u & 3;
    int h   = (u >> 2) & 511;
    int c   = (u >> 11) & 7;
    int mat = u >> 14;                        // 0..2
    bf16x8 v;
#pragma unroll
    for (int i = 0; i < 8; ++i)
        v[i] = (__bf16)W1[(size_t)(mat * 256 + c * 32 + j * 8 + i) * H_DIM + h];
    *(bf16x8*)(W1cc + ((size_t)(mat * 8 + c) * 512 + h) * 32 + j * 8) = v;
}

// ---------------- kernel 2: P = norm(t)@W1a + b1 ; Q = norm(d)@W1b via bf16 MFMA ----------------
// 64 blocks x 512 thr. Block = 64 rows x 256 h (h-half). Wave covers 64 rows x 32 h.
__global__ __launch_bounds__(512, 4)
void pq_mfma_kernel(const float* __restrict__ track, const float* __restrict__ det,
                    const __bf16* __restrict__ W1cc, const float* __restrict__ b1,
                    float* __restrict__ P, float* __restrict__ Q) {
    __shared__ __align__(16) __bf16 Ash[64 * 256];   // 32 KB
    __shared__ float sclS[64];

    int tid  = threadIdx.x;
    int lane = tid & 63;
    int wave = tid >> 6;
    int lq   = lane >> 4;
    int lc   = lane & 15;

    int blk  = blockIdx.x;
    int mat  = blk >> 5;               // 0 = P(track), 1 = Q(det)
    int rowg = (blk >> 1) & 15;
    int half = blk & 1;
    int r0   = rowg * 64;
    int h0   = half * 256;
    const float* src = mat ? det : track;

    // ---- row norms: wave w handles rows w*8 .. w*8+7
#pragma unroll
    for (int i = 0; i < 8; ++i) {
        int row = wave * 8 + i;
        float4 x = ((const float4*)(src + (size_t)(r0 + row) * E_DIM))[lane];
        float ss = x.x*x.x + x.y*x.y + x.z*x.z + x.w*x.w;
#pragma unroll
        for (int off = 32; off > 0; off >>= 1) ss += __shfl_xor(ss, off);
        if (lane == 0) sclS[row] = 1.0f / fmaxf(sqrtf(ss), 1e-12f);
    }
    __syncthreads();

    // ---- A-stage from global, scaled, bf16 (full K for 64 rows)
#pragma unroll
    for (int r = 0; r < 4; ++r) {
        int row = r * 16 + lc;
        float st = sclS[row];
        const float* gp = src + (size_t)(r0 + row) * E_DIM + wave * 32 + lq * 8;
        float4 t0 = *(const float4*)gp;
        float4 t1 = *(const float4*)(gp + 4);
        bf16x8 v;
        v[0] = (__bf16)(t0.x * st); v[1] = (__bf16)(t0.y * st);
        v[2] = (__bf16)(t0.z * st); v[3] = (__bf16)(t0.w * st);
        v[4] = (__bf16)(t1.x * st); v[5] = (__bf16)(t1.y * st);
        v[6] = (__bf16)(t1.z * st); v[7] = (__bf16)(t1.w * st);
        *(bf16x8*)&Ash[(size_t)(r * 512 + wave * 64 + lane) * 8] = v;
    }
    __syncthreads();

    // ---- B = W-frags (register dbuf); frag h = h0 + wave*32 + ht2*16 + lc
    const uint4* Wg = (const uint4*)W1cc + (mat ? 16384 : 0);
    int hb = h0 + wave * 32 + lc;
    bf16x8 bwA[2], bwB[2];
#pragma unroll
    for (int ht = 0; ht < 2; ++ht)
        bwA[ht] = __builtin_bit_cast(bf16x8, Wg[(hb + ht * 16) * 4 + lq]);

    f32x4 acc[4][2];
#pragma unroll
    for (int pt = 0; pt < 4; ++pt)
#pragma unroll
        for (int ht = 0; ht < 2; ++ht)
            acc[pt][ht] = (f32x4){0.f, 0.f, 0.f, 0.f};

#pragma unroll
    for (int c = 0; c < 8; ++c) {
        bf16x8* cur = (c & 1) ? bwB : bwA;
        bf16x8* nxt = (c & 1) ? bwA : bwB;
        if (c < 7) {
#pragma unroll
            for (int ht = 0; ht < 2; ++ht)
                nxt[ht] = __builtin_bit_cast(bf16x8, Wg[(c + 1) * 2048 + (hb + ht * 16) * 4 + lq]);
        }
#pragma unroll
        for (int pt = 0; pt < 4; ++pt) {
            bf16x8 af = *(const bf16x8*)&Ash[(size_t)((pt * 8 + c) * 64 + lane) * 8];
#pragma unroll
            for (int ht = 0; ht < 2; ++ht)
                acc[pt][ht] = __builtin_amdgcn_mfma_f32_16x16x32_bf16(cur[ht], af, acc[pt][ht], 0, 0, 0);
        }
    }

    // ---- store (+bias for P). row = r0 + pt*16+lc, h = h0 + wave*32 + ht2*16 + lq*4 + rg
    float* dst = mat ? Q : P;
#pragma unroll
    for (int ht = 0; ht < 2; ++ht) {
        int h = h0 + wave * 32 + ht * 16 + lq * 4;
        f32x4 bvv = (f32x4){0.f, 0.f, 0.f, 0.f};
        if (!mat) bvv = *(const f32x4*)&b1[h];
#pragma unroll
        for (int pt = 0; pt < 4; ++pt) {
            f32x4 o = acc[pt][ht] + bvv;
            *(f32x4*)&dst[(size_t)(r0 + pt * 16 + lc) * H_DIM + h] = o;
        }
    }
}

// ---------------- kernel 3: fused pairwise GEMM + LN + SiLU + W2 dot ----------------
// grid 2048 x 512 thr (8 waves). Block: 64 pairs x 512 H; K=256, 8 chunks.
// C layout [h x pair]: A = W1c frags (register dbuf), B = |t-d| frags from LDS.
// Element: pair = pt*16+lc (n=pt*2+(lc>>3), m=lc&7); h = wave*64+ht*16+lq*4+rg.
__global__ __launch_bounds__(512, 4)
void main_kernel(const float* __restrict__ track, const float* __restrict__ det,
                 const __bf16* __restrict__ W1cc,
                 const float* __restrict__ P, const float* __restrict__ Q,
                 const float* __restrict__ gamma, const float* __restrict__ beta,
                 const float* __restrict__ W2, const float* __restrict__ b2,
                 float* __restrict__ out) {
    __shared__ __align__(16) char SMEM[49408];
    __bf16* Ash  = (__bf16*)SMEM;                     // [0,32768) phase 1+2
    float*  tsl  = (float*)(SMEM + 32768);            // 8*TSTR f32, phase 1
    float*  dsl  = (float*)(SMEM + 41088);            // phase 1
    float*  LNr1 = (float*)(SMEM + 32768);            // [64][9] phase 2 (tsl dead)
    float*  LNr2 = (float*)(SMEM + 35072);            // [64][9]
    float*  Red2 = (float*)(SMEM + 37376);            // [64][9]
    float*  MuS  = (float*)(SMEM + 39680);            // [64]
    float*  RsS  = (float*)(SMEM + 39936);            // [64]
    __shared__ float sclT[8], sclD[8];

    int tid  = threadIdx.x;
    int lane = tid & 63;
    int wave = tid >> 6;
    int lq   = lane >> 4;
    int lc   = lane & 15;

    int blk = blockIdx.x;
    int b   = blk >> 8;
    int n0  = ((blk >> 4) & 15) * 8;
    int m0  = (blk & 15) * 8;

    // ---- stage loads: wave w holds row w of t-slice and d-slice
    float4 tstage = ((const float4*)(track + (size_t)(b * 128 + n0 + wave) * E_DIM))[lane];
    float4 dstage = ((const float4*)(det   + (size_t)(b * 128 + m0 + wave) * E_DIM))[lane];

    // ---- W1c frags, chunk-0 prefetch (mat 2 base = 32768 uint4)
    const uint4* Wg = (const uint4*)W1cc + 32768;
    int hb = wave * 64 + lc;
    bf16x8 bwA[4], bwB[4];
#pragma unroll
    for (int ht = 0; ht < 4; ++ht)
        bwA[ht] = __builtin_bit_cast(bf16x8, Wg[(hb + ht * 16) * 4 + lq]);

    // ---- row norms from registers
    {
        float a = tstage.x*tstage.x + tstage.y*tstage.y + tstage.z*tstage.z + tstage.w*tstage.w;
        float d = dstage.x*dstage.x + dstage.y*dstage.y + dstage.z*dstage.z + dstage.w*dstage.w;
#pragma unroll
        for (int off = 32; off > 0; off >>= 1) { a += __shfl_xor(a, off); d += __shfl_xor(d, off); }
        if (lane == 0) {
            sclT[wave] = 1.0f / fmaxf(sqrtf(a), 1e-12f);
            sclD[wave] = 1.0f / fmaxf(sqrtf(d), 1e-12f);
        }
    }
    *(float4*)&tsl[wave * TSTR + lane * 4] = tstage;
    *(float4*)&dsl[wave * TSTR + lane * 4] = dstage;
    __syncthreads();

    // ---- A-stage: iter r covers pair p = r*16+lc, k = wave*32+lq*8 .. +7
    {
        int k0 = wave * 32 + lq * 8;
        int ml = lane & 7;
        float sd = sclD[ml];
        const float* dr = dsl + ml * TSTR + k0;
        float4 d0 = *(const float4*)dr;
        float4 d1 = *(const float4*)(dr + 4);
#pragma unroll
        for (int r = 0; r < 4; ++r) {
            int nl = r * 2 + (lc >> 3);
            float st = sclT[nl];
            const float* tr = tsl + nl * TSTR + k0;
            float4 t0 = *(const float4*)tr;
            float4 t1 = *(const float4*)(tr + 4);
            bf16x8 v;
            v[0] = (__bf16)fabsf(t0.x * st - d0.x * sd);
            v[1] = (__bf16)fabsf(t0.y * st - d0.y * sd);
            v[2] = (__bf16)fabsf(t0.z * st - d0.z * sd);
            v[3] = (__bf16)fabsf(t0.w * st - d0.w * sd);
            v[4] = (__bf16)fabsf(t1.x * st - d1.x * sd);
            v[5] = (__bf16)fabsf(t1.y * st - d1.y * sd);
            v[6] = (__bf16)fabsf(t1.z * st - d1.z * sd);
            v[7] = (__bf16)fabsf(t1.w * st - d1.w * sd);
            *(bf16x8*)&Ash[(size_t)(r * 512 + wave * 64 + lane) * 8] = v;
        }
    }
    __syncthreads();

    // ---- K-loop: zero barriers; W1c frags dbuf'd in regs; A reads base+lane*16
    f32x4 acc[4][4];
#pragma unroll
    for (int pt = 0; pt < 4; ++pt)
#pragma unroll
        for (int ht = 0; ht < 4; ++ht)
            acc[pt][ht] = (f32x4){0.f, 0.f, 0.f, 0.f};

#pragma unroll
    for (int c = 0; c < 8; ++c) {
        bf16x8* cur = (c & 1) ? bwB : bwA;
        bf16x8* nxt = (c & 1) ? bwA : bwB;
        if (c < 7) {
#pragma unroll
            for (int ht = 0; ht < 4; ++ht)
                nxt[ht] = __builtin_bit_cast(bf16x8, Wg[(c + 1) * 2048 + (hb + ht * 16) * 4 + lq]);
        }
#pragma unroll
        for (int pt = 0; pt < 4; ++pt) {
            bf16x8 af = *(const bf16x8*)&Ash[(size_t)((pt * 8 + c) * 64 + lane) * 8];
#pragma unroll
            for (int ht = 0; ht < 4; ++ht)
                acc[pt][ht] = __builtin_amdgcn_mfma_f32_16x16x32_bf16(cur[ht], af, acc[pt][ht], 0, 0, 0);
        }
    }

    // ---- phase A: P/Q add straight from global (L2-resident): vector f32x4
    const float* Pb = P + (size_t)(b * 128 + n0) * H_DIM;
    const float* Qb = Q + (size_t)(b * 128 + m0) * H_DIM;
    {
        f32x4 qv[4];
#pragma unroll
        for (int ht = 0; ht < 4; ++ht)
            qv[ht] = *(const f32x4*)&Qb[(size_t)(lc & 7) * H_DIM + wave * 64 + ht * 16 + lq * 4];
#pragma unroll
        for (int pt = 0; pt < 4; ++pt) {
            int n = pt * 2 + (lc >> 3);
#pragma unroll
            for (int ht = 0; ht < 4; ++ht) {
                f32x4 pv = *(const f32x4*)&Pb[(size_t)n * H_DIM + wave * 64 + ht * 16 + lq * 4];
                acc[pt][ht] += pv + qv[ht];
            }
        }
    }

    // ---- phase B: LN partials: in-register sum over 16 h-values, 2 shuffles across lq
#pragma unroll
    for (int pt = 0; pt < 4; ++pt) {
        float s1 = 0.f, s2 = 0.f;
#pragma unroll
        for (int ht = 0; ht < 4; ++ht)
#pragma unroll
            for (int rg = 0; rg < 4; ++rg) {
                float v = acc[pt][ht][rg];
                s1 += v; s2 += v * v;
            }
        s1 += __shfl_xor(s1, 16); s2 += __shfl_xor(s2, 16);
        s1 += __shfl_xor(s1, 32); s2 += __shfl_xor(s2, 32);
        if (lq == 0) {
            LNr1[(pt * 16 + lc) * 9 + wave] = s1;
            LNr2[(pt * 16 + lc) * 9 + wave] = s2;
        }
    }
    __syncthreads();
    if (tid < 64) {
        float S1 = 0.f, S2 = 0.f;
#pragma unroll
        for (int w = 0; w < 8; ++w) { S1 += LNr1[tid * 9 + w]; S2 += LNr2[tid * 9 + w]; }
        float mu = S1 * (1.0f / 512.0f);
        float var = S2 * (1.0f / 512.0f) - mu * mu;
        MuS[tid] = mu;
        RsS[tid] = rsqrtf(var + 1e-5f);
    }
    __syncthreads();

    // ---- phase C: normalize + SiLU + W2 partial dot.
    // Register diet: mus/rss (8) + ca (4) + per-ht g/b/w (12 transient). No 48-reg preload.
    float mus[4], rss[4];
#pragma unroll
    for (int pt = 0; pt < 4; ++pt) { mus[pt] = MuS[pt * 16 + lc]; rss[pt] = RsS[pt * 16 + lc]; }
    float ca[4] = {0.f, 0.f, 0.f, 0.f};
#pragma unroll
    for (int ht = 0; ht < 4; ++ht) {
        int h = wave * 64 + ht * 16 + lq * 4;
        f32x4 g = *(const f32x4*)&gamma[h];
        f32x4 bb = *(const f32x4*)&beta[h];
        f32x4 w = *(const f32x4*)&W2[h];
#pragma unroll
        for (int pt = 0; pt < 4; ++pt) {
#pragma unroll
            for (int rg = 0; rg < 4; ++rg) {
                float x = (acc[pt][ht][rg] - mus[pt]) * rss[pt] * g[rg] + bb[rg];
                float sg = __builtin_amdgcn_rcpf(1.0f + __expf(-x));
                ca[pt] += x * sg * w[rg];
            }
        }
    }
#pragma unroll
    for (int pt = 0; pt < 4; ++pt) {
        float c = ca[pt];
        c += __shfl_xor(c, 16);
        c += __shfl_xor(c, 32);
        if (lq == 0) Red2[(pt * 16 + lc) * 9 + wave] = c;
    }
    __syncthreads();
    if (tid < 64) {
        float o = b2[0];
#pragma unroll
        for (int w = 0; w < 8; ++w) o += Red2[tid * 9 + w];
        int n = n0 + (tid >> 3);
        int m = m0 + (tid & 7);
        out[(size_t)(b * 128 + n) * 128 + m] = o;
    }
}

extern "C" void kernel_launch(void* const* d_in, const int* in_sizes, int n_in,
                              void* d_out, int out_size, void* d_ws, size_t ws_size,
                              hipStream_t stream) {
    const float* track = (const float*)d_in[0];
    const float* det   = (const float*)d_in[1];
    const float* W1    = (const float*)d_in[2];
    const float* b1    = (const float*)d_in[3];
    const float* gamma = (const float*)d_in[4];
    const float* beta  = (const float*)d_in[5];
    const float* W2    = (const float*)d_in[6];
    const float* b2    = (const float*)d_in[7];
    float* out = (float*)d_out;

    char* ws = (char*)d_ws;
    float*  P     = (float*)(ws);                      // 2 MB  (1024 x 512 f32)
    float*  Q     = (float*)(ws + (2u << 20));         // 2 MB
    __bf16* W1cc  = (__bf16*)(ws + (4u << 20));        // 768 KB (bf16 chunk-major, 3 mats)

    w1conv_kernel<<<192, 256, 0, stream>>>(W1, W1cc);
    pq_mfma_kernel<<<64, 512, 0, stream>>>(track, det, W1cc, b1, P, Q);
    main_kernel<<<2048, 512, 0, stream>>>(track, det, W1cc, P, Q, gamma, beta, W2, b2, out);
}